// Round 10
// baseline (1127.172 us; speedup 1.0000x reference)
//
#include <hip/hip_runtime.h>
#include <hip/hip_fp16.h>
#include <math.h>

#define N_NODES 50000
#define N_EDGES 800000
#define D 128
#define T_TYPES 8
#define TPAD 136   // padded LDS row stride (ushorts)
#define NBLK_SCAN 196   // ceil(50000/256)

typedef short short8 __attribute__((ext_vector_type(8)));
typedef float float4v __attribute__((ext_vector_type(4)));
typedef unsigned short ushort_t;

static __device__ __forceinline__ unsigned short f2bf(float f) {
    unsigned u = __float_as_uint(f);
    u += 0x7fff + ((u >> 16) & 1);   // round-to-nearest-even
    return (unsigned short)(u >> 16);
}
static __device__ __forceinline__ float bf2f(unsigned short b) {
    return __uint_as_float((unsigned)b << 16);
}
// exact two-term split: x ~= hi + lo, error <= 2^-18 |x|
static __device__ __forceinline__ void splitbf(float x, unsigned short& hi, unsigned short& lo) {
    unsigned short h_ = f2bf(x);
    hi = h_;
    lo = f2bf(x - bf2f(h_));
}

// ---------------------------------------------------------------------------
__global__ void embed_gather(const int* __restrict__ x, const float* __restrict__ emb,
                             float* __restrict__ h,
                             ushort_t* __restrict__ hhi, ushort_t* __restrict__ hlo) {
    int n = blockIdx.x;
    int d = threadIdx.x;
    float v = emb[(size_t)x[n] * D + d];
    h[(size_t)n * D + d] = v;
    unsigned short a, b;
    splitbf(v, a, b);
    hhi[(size_t)n * D + d] = a;
    hlo[(size_t)n * D + d] = b;
}

// WrelT[t][f][d] = Wrel[t][d][f], split hi/lo bf16
__global__ void convert_wrelT(const float* __restrict__ Wrel,
                              ushort_t* __restrict__ hi, ushort_t* __restrict__ lo) {
    int idx = blockIdx.x * 256 + threadIdx.x; // 0..131071
    int t = idx >> 14;
    int rem = idx & 16383;
    int f = rem >> 7;
    int d = rem & 127;
    unsigned short a, b;
    splitbf(Wrel[((size_t)t << 14) + (d << 7) + f], a, b);
    hi[idx] = a;
    lo[idx] = b;
}

// GRU weights keep [3D][D] layout (already B^T form), split hi/lo
__global__ void convert_w(const float* __restrict__ in,
                          ushort_t* __restrict__ hi, ushort_t* __restrict__ lo, int n) {
    int idx = blockIdx.x * 256 + threadIdx.x;
    if (idx < n) {
        unsigned short a, b;
        splitbf(in[idx], a, b);
        hi[idx] = a;
        lo[idx] = b;
    }
}

// ---------------------------------------------------------------------------
// CSR build over dst
__global__ void count_deg(const int* __restrict__ ei, int* __restrict__ deg) {
    int e = blockIdx.x * 256 + threadIdx.x;
    if (e >= N_EDGES) return;
    atomicAdd(&deg[ei[N_EDGES + e]], 1);
}

__global__ __launch_bounds__(256) void scan_blocks(const int* __restrict__ deg,
                                                   int* __restrict__ bsums) {
    __shared__ int red[4];
    int idx = blockIdx.x * 256 + threadIdx.x;
    int v = (idx < N_NODES) ? deg[idx] : 0;
#pragma unroll
    for (int o = 32; o > 0; o >>= 1) v += __shfl_down(v, o);
    if ((threadIdx.x & 63) == 0) red[threadIdx.x >> 6] = v;
    __syncthreads();
    if (threadIdx.x == 0) bsums[blockIdx.x] = red[0] + red[1] + red[2] + red[3];
}

__global__ __launch_bounds__(256) void scan_tops(int* __restrict__ bsums) {
    __shared__ int s[256];
    int tid = threadIdx.x;
    int v = (tid < NBLK_SCAN) ? bsums[tid] : 0;
    s[tid] = v;
    __syncthreads();
#pragma unroll
    for (int o = 1; o < 256; o <<= 1) {
        int u = (tid >= o) ? s[tid - o] : 0;
        __syncthreads();
        s[tid] += u;
        __syncthreads();
    }
    if (tid < NBLK_SCAN) bsums[tid] = s[tid] - v;   // exclusive
}

__global__ __launch_bounds__(256) void scan_final(const int* __restrict__ bsums,
                                                  int* __restrict__ deg_cursor,
                                                  int* __restrict__ rs) {
    __shared__ int s[256];
    int tid = threadIdx.x;
    int idx = blockIdx.x * 256 + tid;
    int v = (idx < N_NODES) ? deg_cursor[idx] : 0;
    s[tid] = v;
    __syncthreads();
#pragma unroll
    for (int o = 1; o < 256; o <<= 1) {
        int u = (tid >= o) ? s[tid - o] : 0;
        __syncthreads();
        s[tid] += u;
        __syncthreads();
    }
    int excl = s[tid] - v + bsums[blockIdx.x];
    if (idx < N_NODES) {
        rs[idx] = excl;
        deg_cursor[idx] = excl;
    }
    if (idx == 0) rs[N_NODES] = N_EDGES;
}

__global__ void fill_csr(const int* __restrict__ ei, const int* __restrict__ et,
                         int* __restrict__ cursor, int* __restrict__ packed) {
    int e = blockIdx.x * 256 + threadIdx.x;
    if (e >= N_EDGES) return;
    int dst = ei[N_EDGES + e];
    int pos = atomicAdd(&cursor[dst], 1);
    packed[pos] = (ei[e] << 3) | et[e];
}

// ---------------------------------------------------------------------------
// Relational transform, bf16x3 MFMA. Weights staged in LDS (shared by 4 waves).
__global__ __launch_bounds__(256, 2) void gemm_rel(const ushort_t* __restrict__ hhi,
                                                   const ushort_t* __restrict__ hlo,
                                                   const ushort_t* __restrict__ Whi,
                                                   const ushort_t* __restrict__ Wlo,
                                                   ushort_t* __restrict__ Ht) {
    __shared__ __align__(16) ushort_t wlds[2][128 * TPAD];  // hi/lo planes, 69632 B
    const int tid = threadIdx.x;
    const int wave = tid >> 6, lane = tid & 63;
    const int q = lane >> 4, li = lane & 15;
    const int t = blockIdx.y;
    const int m_base = blockIdx.x * 128 + wave * 32;

    {
        const ushort_t* gh = Whi + ((size_t)t << 14);
        const ushort_t* gl = Wlo + ((size_t)t << 14);
#pragma unroll
        for (int i = 0; i < 8; ++i) {
            int g = (i * 256 + tid) * 8;         // 0..16376
            int row = g >> 7, col = g & 127;
            *(short8*)(&wlds[0][row * TPAD + col]) = *(const short8*)(gh + g);
            *(short8*)(&wlds[1][row * TPAD + col]) = *(const short8*)(gl + g);
        }
    }
    __syncthreads();

    int r0 = m_base + li;      if (r0 > N_NODES - 1) r0 = N_NODES - 1;
    int r1 = m_base + 16 + li; if (r1 > N_NODES - 1) r1 = N_NODES - 1;
    const ushort_t* A0h = hhi + (size_t)r0 * D + q * 8;
    const ushort_t* A0l = hlo + (size_t)r0 * D + q * 8;
    const ushort_t* A1h = hhi + (size_t)r1 * D + q * 8;
    const ushort_t* A1l = hlo + (size_t)r1 * D + q * 8;

    short8 a0h[4], a0l[4], a1h[4], a1l[4];
#pragma unroll
    for (int ks = 0; ks < 4; ++ks) {
        a0h[ks] = *(const short8*)(A0h + ks * 32);
        a0l[ks] = *(const short8*)(A0l + ks * 32);
        a1h[ks] = *(const short8*)(A1h + ks * 32);
        a1l[ks] = *(const short8*)(A1l + ks * 32);
    }

    float4v acc[2][8];
#pragma unroll
    for (int m = 0; m < 2; ++m)
#pragma unroll
        for (int ft = 0; ft < 8; ++ft) acc[m][ft] = (float4v){0.f, 0.f, 0.f, 0.f};

#pragma unroll
    for (int ks = 0; ks < 4; ++ks) {
#pragma unroll
        for (int ft = 0; ft < 8; ++ft) {
            const int lo_off = (ft * 16 + li) * TPAD + ks * 32 + q * 8;
            short8 bh = *(const short8*)(&wlds[0][lo_off]);
            short8 bl = *(const short8*)(&wlds[1][lo_off]);
            acc[0][ft] = __builtin_amdgcn_mfma_f32_16x16x32_bf16(a0h[ks], bh, acc[0][ft], 0, 0, 0);
            acc[0][ft] = __builtin_amdgcn_mfma_f32_16x16x32_bf16(a0l[ks], bh, acc[0][ft], 0, 0, 0);
            acc[0][ft] = __builtin_amdgcn_mfma_f32_16x16x32_bf16(a0h[ks], bl, acc[0][ft], 0, 0, 0);
            acc[1][ft] = __builtin_amdgcn_mfma_f32_16x16x32_bf16(a1h[ks], bh, acc[1][ft], 0, 0, 0);
            acc[1][ft] = __builtin_amdgcn_mfma_f32_16x16x32_bf16(a1l[ks], bh, acc[1][ft], 0, 0, 0);
            acc[1][ft] = __builtin_amdgcn_mfma_f32_16x16x32_bf16(a1h[ks], bl, acc[1][ft], 0, 0, 0);
        }
    }

    __syncthreads();   // all weight ds_reads done -> reuse LDS for epilogue
    ushort_t* tw = &wlds[0][0] + wave * 32 * TPAD;
#pragma unroll
    for (int m = 0; m < 2; ++m)
#pragma unroll
        for (int ft = 0; ft < 8; ++ft)
#pragma unroll
            for (int r = 0; r < 4; ++r) {
                __half hv = __float2half_rn(acc[m][ft][r]);
                tw[(m * 16 + q * 4 + r) * TPAD + ft * 16 + li] = __half_as_ushort(hv);
            }
#pragma unroll
    for (int i = 0; i < 8; ++i) {
        int row = i * 4 + q;       // 0..31
        int col = li * 8;
        short8 v = *(const short8*)(tw + row * TPAD + col);
        int orow = m_base + row;
        if (orow < N_NODES)
            *(short8*)(Ht + (size_t)orow * 1024 + (t << 7) + col) = v;
    }
}

// ---------------------------------------------------------------------------
// CSR aggregation: one wave per dst node; fp16 Ht gather, fp32 accumulate,
// pre-split bf16 hi/lo output. Fuses b_node bias.
__global__ __launch_bounds__(256) void aggregate_csr(const int* __restrict__ rs,
                                                     const int* __restrict__ packed,
                                                     const ushort_t* __restrict__ Ht,
                                                     const int* __restrict__ nt,
                                                     const float* __restrict__ b_node,
                                                     ushort_t* __restrict__ ahi,
                                                     ushort_t* __restrict__ alo) {
    int n = blockIdx.x * 4 + (threadIdx.x >> 6);
    if (n >= N_NODES) return;
    const int lane = threadIdx.x & 63;
    const int beg = rs[n], end = rs[n + 1];
    const __half2* Ht2 = (const __half2*)Ht;

    float2 acc = ((const float2*)(b_node + (size_t)nt[n] * D))[lane];

    int i = beg;
    for (; i + 3 < end; i += 4) {
        int p0 = packed[i], p1 = packed[i + 1], p2 = packed[i + 2], p3 = packed[i + 3];
        float2 f0 = __half22float2(Ht2[(size_t)p0 * 64 + lane]);
        float2 f1 = __half22float2(Ht2[(size_t)p1 * 64 + lane]);
        float2 f2 = __half22float2(Ht2[(size_t)p2 * 64 + lane]);
        float2 f3 = __half22float2(Ht2[(size_t)p3 * 64 + lane]);
        acc.x += (f0.x + f1.x) + (f2.x + f3.x);
        acc.y += (f0.y + f1.y) + (f2.y + f3.y);
    }
    for (; i < end; ++i) {
        int pk = packed[i];
        float2 fv = __half22float2(Ht2[(size_t)pk * 64 + lane]);
        acc.x += fv.x;
        acc.y += fv.y;
    }

    unsigned short h0, l0, h1, l1;
    splitbf(acc.x, h0, l0);
    splitbf(acc.y, h1, l1);
    ((unsigned*)ahi)[(size_t)n * 64 + lane] = (unsigned)h0 | ((unsigned)h1 << 16);
    ((unsigned*)alo)[(size_t)n * 64 + lane] = (unsigned)l0 | ((unsigned)l1 << 16);
}

// ---------------------------------------------------------------------------
// Fused GRU, bf16x3 MFMA. Block = 512 thr = 8 waves, 64 rows x 128 cols.
// x-state staged in LDS; ALL 48 weight frags hoisted to registers before the
// k-loop. launch_bounds(512,1): 512-VGPR budget so the hoist sticks (R9's
// VGPR=84 re-loaded weights from L2 inside the loop -> MfmaUtil 13%).
__global__ __launch_bounds__(512, 1) void gru_mfma(const ushort_t* __restrict__ ahi,
                                                   const ushort_t* __restrict__ alo,
                                                   ushort_t* __restrict__ hhi,
                                                   ushort_t* __restrict__ hlo,
                                                   const ushort_t* __restrict__ Wihi,
                                                   const ushort_t* __restrict__ Wilo,
                                                   const ushort_t* __restrict__ Whhi,
                                                   const ushort_t* __restrict__ Whlo,
                                                   const float* __restrict__ b_ih,
                                                   const float* __restrict__ b_hh,
                                                   float* __restrict__ h) {
    __shared__ __align__(16) ushort_t xlds[4][64 * TPAD];  // 69632 B
    const int tid = threadIdx.x;
    const int wave = tid >> 6, lane = tid & 63;
    const int q = lane >> 4, li = lane & 15;
    const int n0 = blockIdx.x * 64;
    const int f = wave * 16 + li;

    // ---- stage x-state: 4 arrays x 8192 ushorts; 512 thr x 2 x short8 each ----
#pragma unroll
    for (int i = 0; i < 2; ++i) {
        int g = (i * 512 + tid) * 8;   // 0..8184
        int row = g >> 7, col = g & 127;
        int gr = n0 + row;
        if (gr > N_NODES - 1) gr = N_NODES - 1;
        size_t go = (size_t)gr * D + col;
        int la = row * TPAD + col;
        *(short8*)(&xlds[0][la]) = *(const short8*)(ahi + go);
        *(short8*)(&xlds[1][la]) = *(const short8*)(alo + go);
        *(short8*)(&xlds[2][la]) = *(const short8*)(hhi + go);
        *(short8*)(&xlds[3][la]) = *(const short8*)(hlo + go);
    }

    // ---- hoist ALL weight fragments (loop-invariant) into registers ----
    const size_t oR = (size_t)f * D + q * 8;
    const size_t oZ = (size_t)(D + f) * D + q * 8;
    const size_t oN = (size_t)(2 * D + f) * D + q * 8;

    short8 wIRh[4], wIRl[4], wHRh[4], wHRl[4];
    short8 wIZh[4], wIZl[4], wHZh[4], wHZl[4];
    short8 wINh[4], wINl[4], wHNh[4], wHNl[4];
#pragma unroll
    for (int ks = 0; ks < 4; ++ks) {
        const int off = ks * 32;
        wIRh[ks] = *(const short8*)(Wihi + oR + off);
        wIRl[ks] = *(const short8*)(Wilo + oR + off);
        wHRh[ks] = *(const short8*)(Whhi + oR + off);
        wHRl[ks] = *(const short8*)(Whlo + oR + off);
        wIZh[ks] = *(const short8*)(Wihi + oZ + off);
        wIZl[ks] = *(const short8*)(Wilo + oZ + off);
        wHZh[ks] = *(const short8*)(Whhi + oZ + off);
        wHZl[ks] = *(const short8*)(Whlo + oZ + off);
        wINh[ks] = *(const short8*)(Wihi + oN + off);
        wINl[ks] = *(const short8*)(Wilo + oN + off);
        wHNh[ks] = *(const short8*)(Whhi + oN + off);
        wHNl[ks] = *(const short8*)(Whlo + oN + off);
    }

    __syncthreads();   // x-state staged (overlaps the weight loads above)

    float4v aR[4], aZ[4], aI[4], aH[4];
#pragma unroll
    for (int m = 0; m < 4; ++m) {
        aR[m] = (float4v){0.f, 0.f, 0.f, 0.f};
        aZ[m] = aR[m]; aI[m] = aR[m]; aH[m] = aR[m];
    }

#pragma unroll
    for (int ks = 0; ks < 4; ++ks) {
        const int off = ks * 32;
#pragma unroll
        for (int m = 0; m < 4; ++m) {
            const int lo_off = (m * 16 + li) * TPAD + off + q * 8;
            short8 xah = *(const short8*)(&xlds[0][lo_off]);
            short8 xal = *(const short8*)(&xlds[1][lo_off]);
            short8 xhh = *(const short8*)(&xlds[2][lo_off]);
            short8 xhl = *(const short8*)(&xlds[3][lo_off]);
            aR[m] = __builtin_amdgcn_mfma_f32_16x16x32_bf16(xah, wIRh[ks], aR[m], 0, 0, 0);
            aR[m] = __builtin_amdgcn_mfma_f32_16x16x32_bf16(xal, wIRh[ks], aR[m], 0, 0, 0);
            aR[m] = __builtin_amdgcn_mfma_f32_16x16x32_bf16(xah, wIRl[ks], aR[m], 0, 0, 0);
            aR[m] = __builtin_amdgcn_mfma_f32_16x16x32_bf16(xhh, wHRh[ks], aR[m], 0, 0, 0);
            aR[m] = __builtin_amdgcn_mfma_f32_16x16x32_bf16(xhl, wHRh[ks], aR[m], 0, 0, 0);
            aR[m] = __builtin_amdgcn_mfma_f32_16x16x32_bf16(xhh, wHRl[ks], aR[m], 0, 0, 0);
            aZ[m] = __builtin_amdgcn_mfma_f32_16x16x32_bf16(xah, wIZh[ks], aZ[m], 0, 0, 0);
            aZ[m] = __builtin_amdgcn_mfma_f32_16x16x32_bf16(xal, wIZh[ks], aZ[m], 0, 0, 0);
            aZ[m] = __builtin_amdgcn_mfma_f32_16x16x32_bf16(xah, wIZl[ks], aZ[m], 0, 0, 0);
            aZ[m] = __builtin_amdgcn_mfma_f32_16x16x32_bf16(xhh, wHZh[ks], aZ[m], 0, 0, 0);
            aZ[m] = __builtin_amdgcn_mfma_f32_16x16x32_bf16(xhl, wHZh[ks], aZ[m], 0, 0, 0);
            aZ[m] = __builtin_amdgcn_mfma_f32_16x16x32_bf16(xhh, wHZl[ks], aZ[m], 0, 0, 0);
            aI[m] = __builtin_amdgcn_mfma_f32_16x16x32_bf16(xah, wINh[ks], aI[m], 0, 0, 0);
            aI[m] = __builtin_amdgcn_mfma_f32_16x16x32_bf16(xal, wINh[ks], aI[m], 0, 0, 0);
            aI[m] = __builtin_amdgcn_mfma_f32_16x16x32_bf16(xah, wINl[ks], aI[m], 0, 0, 0);
            aH[m] = __builtin_amdgcn_mfma_f32_16x16x32_bf16(xhh, wHNh[ks], aH[m], 0, 0, 0);
            aH[m] = __builtin_amdgcn_mfma_f32_16x16x32_bf16(xhl, wHNh[ks], aH[m], 0, 0, 0);
            aH[m] = __builtin_amdgcn_mfma_f32_16x16x32_bf16(xhh, wHNl[ks], aH[m], 0, 0, 0);
        }
    }

    const float bR = b_ih[f] + b_hh[f];
    const float bZ = b_ih[D + f] + b_hh[D + f];
    const float bIn = b_ih[2 * D + f];
    const float bHn = b_hh[2 * D + f];

    // hold reconstructed from staged hi/lo (error 2^-18 — invisible at current
    // absmax floor) — deletes 16 scalar global fp32 reads per lane.
#pragma unroll
    for (int m = 0; m < 4; ++m) {
#pragma unroll
        for (int r = 0; r < 4; ++r) {
            int node = n0 + m * 16 + q * 4 + r;
            if (node < N_NODES) {
                int la = (m * 16 + q * 4 + r) * TPAD + f;
                float hold = bf2f(xlds[2][la]) + bf2f(xlds[3][la]);
                float rg = 1.0f / (1.0f + __expf(-(aR[m][r] + bR)));
                float zg = 1.0f / (1.0f + __expf(-(aZ[m][r] + bZ)));
                float narg = aI[m][r] + bIn + rg * (aH[m][r] + bHn);
                float ex = __expf(2.0f * narg);
                float ng = 1.0f - 2.0f / (ex + 1.0f);   // tanh
                float hn = (1.0f - zg) * ng + zg * hold;
                h[(size_t)node * D + f] = hn;
                unsigned short sh, sl;
                splitbf(hn, sh, sl);
                hhi[(size_t)node * D + f] = sh;
                hlo[(size_t)node * D + f] = sl;
            }
        }
    }
}

// ---------------------------------------------------------------------------
extern "C" void kernel_launch(void* const* d_in, const int* in_sizes, int n_in,
                              void* d_out, int out_size, void* d_ws, size_t ws_size,
                              hipStream_t stream) {
    const int* x      = (const int*)d_in[0];
    const int* ei     = (const int*)d_in[1];
    const int* et     = (const int*)d_in[2];
    const int* nt     = (const int*)d_in[3];
    const float* emb  = (const float*)d_in[4];
    const float* Wrel = (const float*)d_in[5];
    const float* b_node = (const float*)d_in[6];
    const float* W_ih = (const float*)d_in[7];
    const float* W_hh = (const float*)d_in[8];
    const float* b_ih = (const float*)d_in[9];
    const float* b_hh = (const float*)d_in[10];

    float* h = (float*)d_out;
    float* ws = (float*)d_ws;

    // workspace layout (total ~158 MB, well under proven >=234 MB)
    ushort_t* Ht = (ushort_t*)ws;                          // 51,200,000 us (fp16)
    ushort_t* us = (ushort_t*)(ws + 25600000);
    ushort_t* ahi  = us;                                   // 6,400,000 each
    ushort_t* alo  = us + 6400000;
    ushort_t* hhi  = us + 12800000;
    ushort_t* hlo  = us + 19200000;
    ushort_t* Whi  = us + 25600000;                        //   131,072 each
    ushort_t* Wlo  = Whi + 131072;
    ushort_t* Wihi = Wlo + 131072;                         //    49,152 each
    ushort_t* Wilo = Wihi + 49152;
    ushort_t* Whhi = Wilo + 49152;
    ushort_t* Whlo = Whhi + 49152;
    int* rs     = (int*)(ws + 38629376);                   //    50,004
    int* packed = rs + 50004;                              //   800,000
    int* bsums  = packed + 800000;                         //       256
    int* deg    = (int*)ws;                                // transient alias in Ht region (pre-loop only)

    convert_wrelT<<<512, 256, 0, stream>>>(Wrel, Whi, Wlo);
    convert_w<<<192, 256, 0, stream>>>(W_ih, Wihi, Wilo, 3 * D * D);
    convert_w<<<192, 256, 0, stream>>>(W_hh, Whhi, Whlo, 3 * D * D);
    embed_gather<<<N_NODES, 128, 0, stream>>>(x, emb, h, hhi, hlo);

    hipMemsetAsync(deg, 0, 50000 * sizeof(int), stream);
    count_deg<<<3125, 256, 0, stream>>>(ei, deg);
    scan_blocks<<<NBLK_SCAN, 256, 0, stream>>>(deg, bsums);
    scan_tops<<<1, 256, 0, stream>>>(bsums);
    scan_final<<<NBLK_SCAN, 256, 0, stream>>>(bsums, deg, rs);   // cursor aliases deg
    fill_csr<<<3125, 256, 0, stream>>>(ei, et, deg, packed);

    for (int it = 0; it < 5; ++it) {
        dim3 g(391, T_TYPES);   // 391*128 = 50048 rows
        gemm_rel<<<g, 256, 0, stream>>>(hhi, hlo, Whi, Wlo, Ht);
        aggregate_csr<<<12500, 256, 0, stream>>>(rs, packed, Ht, nt, b_node, ahi, alo);
        gru_mfma<<<782, 512, 0, stream>>>(ahi, alo, hhi, hlo,
                                          Wihi, Wilo, Whhi, Whlo, b_ih, b_hh, h);
    }
}